// Round 1
// baseline (94.686 us; speedup 1.0000x reference)
//
#include <hip/hip_runtime.h>
#include <math.h>

// TripletHard B=8192 D=128 NC=256. Round-20: FUSE pos into main epilogue.
// The main path computes the full 8192x8192 Gram (16 stripes x 512 cols);
// same-class pairs were masked to INF and then RECOMPUTED by 256 dedicated
// pos blocks (label scan + scattered gathers) that ran as a latency-bound
// second generation after the 512 main blocks drained (r17: "3rd CU slot
// sat empty after pos drained"). Instead: track the two smallest same-class
// v = sj - 2*acc online in the main epilogue (+4 VALU/elem), 2-min
// shuffle-merge across the 16 c-lanes, write (n1,s1,s2) per stripe, and
// 2-min-merge stripes in merge_kernel. Grid 768->512 = exactly 2/CU,
// uniform drain, no tail. Same bf16 frags through the same ks-chain ->
// same-class v bitwise identical to old pos path -> absmax stays 0.
//   prep : fp32->bf16 (RNE), K-major fbT, lsq=(sq,lblbits) of rounded values.
//   work : 512 blocks, wave tile 64x32 (mf=4, nf=2), A-frags resident
//          (lb(256,2), r19 fix), B via LDS dbuf, 16 jt.
//   merge: combine 16 (n1,s1,s2) slices -> mean hinge (device atomics).
// fbT8[kc*8192 + row] = features[row][kc*8..kc*8+7], kc=0..15.

#define BN 8192
#define MARGIN_F 1.0f
#define EPS_F 1e-5f

typedef __attribute__((ext_vector_type(8))) short short8;
typedef __attribute__((ext_vector_type(4))) float floatx4;

__device__ __forceinline__ unsigned short bf16_rne(float x, float& r) {
    unsigned u = __float_as_uint(x);
    u += 0x7FFF + ((u >> 16) & 1);
    unsigned short h = (unsigned short)(u >> 16);
    r = __uint_as_float(((unsigned)h) << 16);
    return h;
}

// 8 threads/row (256 blocks): bf16 convert, K-major write, lsq=(sq, lblbits)
// from ROUNDED values. Also zero-inits g_acc/counter.
__global__ __launch_bounds__(256) void prep_kernel(const float* __restrict__ f,
                                                   const int* __restrict__ lbl,
                                                   short8* __restrict__ fbT,
                                                   float2* __restrict__ lsq,
                                                   float* __restrict__ g_acc,
                                                   unsigned* __restrict__ counter) {
    int gid = blockIdx.x * 256 + threadIdx.x;  // 0..65535
    if (gid == 0) { *g_acc = 0.f; *counter = 0u; }
    int row = gid >> 3, part = gid & 7;
    const float4* f4 = (const float4*)f + (size_t)row * 32 + part * 4;
    float s = 0.f;
#pragma unroll
    for (int cc = 0; cc < 2; ++cc) {  // chunk kc = part*2 + cc
        float4 v0 = f4[cc * 2], v1 = f4[cc * 2 + 1];
        float r0, r1, r2, r3, r4, r5, r6, r7;
        short8 o;
        o[0] = (short)bf16_rne(v0.x, r0);
        o[1] = (short)bf16_rne(v0.y, r1);
        o[2] = (short)bf16_rne(v0.z, r2);
        o[3] = (short)bf16_rne(v0.w, r3);
        o[4] = (short)bf16_rne(v1.x, r4);
        o[5] = (short)bf16_rne(v1.y, r5);
        o[6] = (short)bf16_rne(v1.z, r6);
        o[7] = (short)bf16_rne(v1.w, r7);
        fbT[(size_t)(part * 2 + cc) * BN + row] = o;
        s += r0 * r0 + r1 * r1 + r2 * r2 + r3 * r3 +
             r4 * r4 + r5 * r5 + r6 * r6 + r7 * r7;
    }
    s += __shfl_xor(s, 1, 8);
    s += __shfl_xor(s, 2, 8);
    s += __shfl_xor(s, 4, 8);
    if (part == 0) {
        float2 p;
        p.x = s;
        p.y = __int_as_float(lbl[row]);
        lsq[row] = p;
    }
}

// Stage one 32-col B-tile (16 chunks x 32 cols = 8 KB) into LDS: each wave
// issues 2 global_load_lds(16B). LDS dest is wave-uniform; HW adds lane*16.
// Layout: tile[kc*32 + col], kc = lane>>5 within each 64-slot instr.
__device__ __forceinline__ void stage_tile(const short8* __restrict__ fbT,
                                           short8* tile, int j0, int wv, int lane) {
#pragma unroll
    for (int it = 0; it < 2; ++it) {
        int s = wv * 128 + it * 64;  // wave-uniform slot base
        int kc = (s >> 5) + (lane >> 5);
        int col = lane & 31;
        const short8* g = fbT + ((size_t)kc * BN + j0 + col);
        __builtin_amdgcn_global_load_lds(
            (const __attribute__((address_space(1))) void*)g,
            (__attribute__((address_space(3))) void*)(tile + s),
            16, 0, 0);
    }
}

// Fused work kernel: 512 uniform blocks (2/CU), wave tile 64x32.
// Per element track: n1 = min diff-class v, (s1,s2) = two smallest
// same-class v (self-pair included, as the reference requires).
__global__ __launch_bounds__(256, 2) void work_kernel(const short8* __restrict__ fbT,
                                                      const float2* __restrict__ lsq,
                                                      float* __restrict__ part_n1,
                                                      float* __restrict__ part_s1,
                                                      float* __restrict__ part_s2) {
    const int t = threadIdx.x;
    const int lane = t & 63;
    const int wv = t >> 6;
    const int q = lane >> 4, c = lane & 15;
    const int bid = blockIdx.x;

    __shared__ short8 Bt[2][512];    // 2 x 8 KB, [kc*32 + col]
    __shared__ float2 lsq_sh[512];   // block's j-stripe (sq, lblbits)

    const int i0 = (bid & 31) * 256 + wv * 64;  // 32 i-blocks x 4 waves x 64 rows
    const int g = bid >> 5;  // 0..15
    const int jb = g * 512;

    stage_tile(fbT, Bt[0], jb, wv, lane);  // tile 0 in flight

    // stage the whole stripe's (sq,label) once: 512 float2, 2 per thread
    lsq_sh[t] = lsq[jb + t];
    lsq_sh[t + 256] = lsq[jb + t + 256];

    short8 a[4][4];
#pragma unroll
    for (int mf = 0; mf < 4; ++mf) {
        int row = i0 + mf * 16 + c;
#pragma unroll
        for (int ks = 0; ks < 4; ++ks)
            a[mf][ks] = fbT[(size_t)(ks * 4 + q) * BN + row];
    }
    int li[4][4];
#pragma unroll
    for (int mf = 0; mf < 4; ++mf)
#pragma unroll
        for (int rg = 0; rg < 4; ++rg)
            li[mf][rg] = __float_as_int(lsq[i0 + mf * 16 + q * 4 + rg].y);

    float n1[4][4], s1[4][4], s2[4][4];
#pragma unroll
    for (int mf = 0; mf < 4; ++mf)
#pragma unroll
        for (int rg = 0; rg < 4; ++rg) {
            n1[mf][rg] = INFINITY;
            s1[mf][rg] = INFINITY;
            s2[mf][rg] = INFINITY;
        }

    __syncthreads();  // tile 0 + lsq_sh resident

    for (int jt = 0; jt < 16; ++jt) {
        const short8* cur = Bt[jt & 1];
        const int j0 = jb + jt * 32;
        // prefetch next tile NOW; it lands during this tile's compute
        if (jt < 15) stage_tile(fbT, Bt[1 - (jt & 1)], j0 + 32, wv, lane);

        int ljv[2]; float sjv[2];
#pragma unroll
        for (int nf = 0; nf < 2; ++nf) {
            float2 p = lsq_sh[jt * 32 + nf * 16 + c];  // LDS, no global latency
            sjv[nf] = p.x;
            ljv[nf] = __float_as_int(p.y);
        }

        floatx4 acc[4][2];
#pragma unroll
        for (int mf = 0; mf < 4; ++mf)
#pragma unroll
            for (int nf = 0; nf < 2; ++nf) acc[mf][nf] = (floatx4)0.f;

#pragma unroll
        for (int ks = 0; ks < 4; ++ks) {
            short8 b[2];
#pragma unroll
            for (int nf = 0; nf < 2; ++nf)
                b[nf] = cur[(ks * 4 + q) * 32 + nf * 16 + c];
#pragma unroll
            for (int mf = 0; mf < 4; ++mf)
#pragma unroll
                for (int nf = 0; nf < 2; ++nf)
                    acc[mf][nf] = __builtin_amdgcn_mfma_f32_16x16x32_bf16(
                        a[mf][ks], b[nf], acc[mf][nf], 0, 0, 0);
        }

        // fused epilogue: diff-class running min + same-class online 2-min
#pragma unroll
        for (int nf = 0; nf < 2; ++nf) {
#pragma unroll
            for (int mf = 0; mf < 4; ++mf)
#pragma unroll
                for (int rg = 0; rg < 4; ++rg) {
                    float v = fmaf(-2.0f, acc[mf][nf][rg], sjv[nf]);
                    bool same = (li[mf][rg] == ljv[nf]);
                    float vd = same ? INFINITY : v;
                    float vs = same ? v : INFINITY;
                    n1[mf][rg] = fminf(n1[mf][rg], vd);
                    s2[mf][rg] = fminf(s2[mf][rg], fmaxf(s1[mf][rg], vs));
                    s1[mf][rg] = fminf(s1[mf][rg], vs);
                }
        }
        // barrier at END: stage had the whole compute to land -> drain ~free
        __syncthreads();
    }

    // reduce across the 16 c-lanes sharing each accumulator row:
    // min for n1, two-smallest merge for (s1,s2)
#pragma unroll
    for (int m = 1; m < 16; m <<= 1) {
#pragma unroll
        for (int mf = 0; mf < 4; ++mf)
#pragma unroll
            for (int rg = 0; rg < 4; ++rg) {
                n1[mf][rg] = fminf(n1[mf][rg], __shfl_xor(n1[mf][rg], m, 16));
                float o1 = __shfl_xor(s1[mf][rg], m, 16);
                float o2 = __shfl_xor(s2[mf][rg], m, 16);
                float hi = fminf(fmaxf(s1[mf][rg], o1), fminf(s2[mf][rg], o2));
                s1[mf][rg] = fminf(s1[mf][rg], o1);
                s2[mf][rg] = hi;
            }
    }
    if (c == 0) {
#pragma unroll
        for (int mf = 0; mf < 4; ++mf)
#pragma unroll
            for (int rg = 0; rg < 4; ++rg) {
                int idx = g * BN + i0 + mf * 16 + q * 4 + rg;
                part_n1[idx] = n1[mf][rg];
                part_s1[idx] = s1[mf][rg];
                part_s2[idx] = s2[mf][rg];
            }
    }
}

// combine 16 (n1,s1,s2) slices -> hinge; atomic sum; last block writes mean
__global__ __launch_bounds__(128) void merge_kernel(const float* __restrict__ part_n1,
                                                    const float* __restrict__ part_s1,
                                                    const float* __restrict__ part_s2,
                                                    const float2* __restrict__ lsq,
                                                    float* __restrict__ g_acc,
                                                    unsigned* __restrict__ counter,
                                                    float* __restrict__ out) {
    int r = blockIdx.x * 128 + threadIdx.x;
    float n = INFINITY, s1 = INFINITY, s2 = INFINITY;
#pragma unroll
    for (int k = 0; k < 16; ++k) {
        n = fminf(n, part_n1[k * BN + r]);
        float a1 = part_s1[k * BN + r];
        float a2 = part_s2[k * BN + r];
        s2 = fminf(fmaxf(s1, a1), fminf(s2, a2));
        s1 = fminf(s1, a1);
    }
    float si = lsq[r].x;
    float pos = sqrtf(fmaxf(si + s2 + EPS_F, 0.f));
    float neg = sqrtf(fmaxf(si + n + EPS_F, 0.f));
    float h = fmaxf(MARGIN_F + pos - neg, 0.f);
    __shared__ float red[2];
#pragma unroll
    for (int m = 32; m >= 1; m >>= 1) h += __shfl_down(h, m, 64);
    if ((threadIdx.x & 63) == 0) red[threadIdx.x >> 6] = h;
    __syncthreads();
    if (threadIdx.x == 0) {
        atomicAdd(g_acc, red[0] + red[1]);
        __threadfence();
        unsigned old = atomicAdd(counter, 1u);
        if (old == 63u) {
            float tot = atomicAdd(g_acc, 0.0f);
            out[0] = tot / (float)BN;
        }
    }
}

extern "C" void kernel_launch(void* const* d_in, const int* in_sizes, int n_in,
                              void* d_out, int out_size, void* d_ws, size_t ws_size,
                              hipStream_t stream) {
    const float* f = (const float*)d_in[0];
    const int* lbl = (const int*)d_in[1];
    char* ws = (char*)d_ws;
    float2* lsq = (float2*)ws;                                  // 64 KB
    short8* fbT = (short8*)(ws + 65536);                        // 2 MB
    float* part_n1 = (float*)(ws + 65536 + 2097152);            // 512 KB
    float* part_s1 = (float*)(ws + 65536 + 2097152 + 524288);   // 512 KB
    float* part_s2 = (float*)(ws + 65536 + 2097152 + 1048576);  // 512 KB
    float* g_acc = (float*)(ws + 65536 + 2097152 + 1572864);
    unsigned* counter = (unsigned*)(g_acc + 1);
    float* out = (float*)d_out;

    prep_kernel<<<256, 256, 0, stream>>>(f, lbl, fbT, lsq, g_acc, counter);
    work_kernel<<<512, 256, 0, stream>>>(fbT, lsq, part_n1, part_s1, part_s2);
    merge_kernel<<<64, 128, 0, stream>>>(part_n1, part_s1, part_s2, lsq, g_acc, counter, out);
}